// Round 1
// baseline (417.273 us; speedup 1.0000x reference)
//
#include <hip/hip_runtime.h>
#include <math.h>

#define Hdim 1024
#define Vdim 50257
#define Ldim 512

// ---------- reduction helpers (wave = 64) ----------
__device__ __forceinline__ float waveReduceSum(float v) {
    #pragma unroll
    for (int off = 32; off > 0; off >>= 1) v += __shfl_down(v, off, 64);
    return v;
}
__device__ __forceinline__ float waveReduceMax(float v) {
    #pragma unroll
    for (int off = 32; off > 0; off >>= 1) v = fmaxf(v, __shfl_down(v, off, 64));
    return v;
}
// block reduce for blockDim = NW*64; result broadcast to all threads; safe to
// call repeatedly with the same `red` buffer (2 syncs bracket the reads).
template<int NW>
__device__ __forceinline__ float blockReduceSum(float v, float* red) {
    v = waveReduceSum(v);
    const int lane = threadIdx.x & 63, wid = threadIdx.x >> 6;
    if (lane == 0) red[wid] = v;
    __syncthreads();
    float s = red[0];
    #pragma unroll
    for (int i = 1; i < NW; i++) s += red[i];
    __syncthreads();
    return s;
}

// ---------- K1: att[l] = Ww[l,:]·[emb[x];hidden] + bw[l]  (blocks 0..511)
//             gh[r]  = Whh[r,:]·hidden + bhh[r]            (blocks 512..3583)
__global__ __launch_bounds__(256) void k_att_gh(
    const int* __restrict__ xp, const float* __restrict__ hidden,
    const float* __restrict__ emb, const float* __restrict__ Ww,
    const float* __restrict__ bw, const float* __restrict__ Whh,
    const float* __restrict__ bhh, float* __restrict__ att, float* __restrict__ gh)
{
    __shared__ float red[4];
    const int t = threadIdx.x, bid = blockIdx.x;
    float acc = 0.f;
    if (bid < Ldim) {
        const int tok = xp[0];
        const float4* wrow = (const float4*)(Ww + (size_t)bid * (2 * Hdim));
        const float4* ev   = (const float4*)(emb + (size_t)tok * Hdim);
        const float4* hv   = (const float4*)hidden;
        #pragma unroll
        for (int k = 0; k < 2; ++k) {
            const int j = t * 2 + k;                       // 0..511 float4s
            const float4 w = wrow[j];
            const float4 c = (j < Hdim / 4) ? ev[j] : hv[j - Hdim / 4];
            acc += w.x * c.x + w.y * c.y + w.z * c.z + w.w * c.w;
        }
        acc = blockReduceSum<4>(acc, red);
        if (t == 0) att[bid] = acc + bw[bid];
    } else {
        const int r = bid - Ldim;
        const float4* wrow = (const float4*)(Whh + (size_t)r * Hdim);
        const float4 w = wrow[t];
        const float4 h = ((const float4*)hidden)[t];
        acc = w.x * h.x + w.y * h.y + w.z * h.z + w.w * h.w;
        acc = blockReduceSum<4>(acc, red);
        if (t == 0) gh[r] = acc + bhh[r];
    }
}

// ---------- K2: weights = softmax(att); also zero wctx accumulator ----------
__global__ __launch_bounds__(512) void k_softmax(
    const float* __restrict__ att, float* __restrict__ weights,
    float* __restrict__ out_w, float* __restrict__ wctx)
{
    __shared__ float red[8];
    __shared__ float bm, bs;
    const int t = threadIdx.x;                              // 512 threads
    const float v = att[t];
    float m = waveReduceMax(v);
    if ((t & 63) == 0) red[t >> 6] = m;
    __syncthreads();
    if (t == 0) {
        float mm = red[0];
        #pragma unroll
        for (int i = 1; i < 8; i++) mm = fmaxf(mm, red[i]);
        bm = mm;
    }
    __syncthreads();
    const float e = __expf(v - bm);
    float s = waveReduceSum(e);
    __syncthreads();
    if ((t & 63) == 0) red[t >> 6] = s;
    __syncthreads();
    if (t == 0) {
        float ss = red[0];
        #pragma unroll
        for (int i = 1; i < 8; i++) ss += red[i];
        bs = ss;
    }
    __syncthreads();
    const float w = e / bs;
    weights[t] = w;
    out_w[t]   = w;                                         // output 3
    wctx[t] = 0.f; wctx[t + 512] = 0.f;                     // init accumulator
}

// ---------- K3: wctx[i] += sum over 8 rows of w[l]*enc[l,i] (64 blocks) ----
__global__ __launch_bounds__(256) void k_wctx(
    const float* __restrict__ weights, const float* __restrict__ enc,
    float* __restrict__ wctx)
{
    const int b = blockIdx.x, t = threadIdx.x;
    float4 acc = make_float4(0.f, 0.f, 0.f, 0.f);
    #pragma unroll
    for (int i = 0; i < 8; ++i) {
        const int l = b * 8 + i;
        const float w = weights[l];
        const float4 e = ((const float4*)(enc + (size_t)l * Hdim))[t];
        acc.x += w * e.x; acc.y += w * e.y; acc.z += w * e.z; acc.w += w * e.w;
    }
    atomicAdd(&wctx[t * 4 + 0], acc.x);
    atomicAdd(&wctx[t * 4 + 1], acc.y);
    atomicAdd(&wctx[t * 4 + 2], acc.z);
    atomicAdd(&wctx[t * 4 + 3], acc.w);
}

// ---------- K4: c[r] = relu(Wc[r,:]·[emb[x];wctx] + bc[r]) (1024 blocks) ---
__global__ __launch_bounds__(256) void k_wc(
    const int* __restrict__ xp, const float* __restrict__ emb,
    const float* __restrict__ wctx, const float* __restrict__ Wc,
    const float* __restrict__ bc, float* __restrict__ cvec)
{
    __shared__ float red[4];
    const int t = threadIdx.x, r = blockIdx.x;
    const int tok = xp[0];
    const float4* wrow = (const float4*)(Wc + (size_t)r * (2 * Hdim));
    const float4* ev   = (const float4*)(emb + (size_t)tok * Hdim);
    const float4* cv   = (const float4*)wctx;
    float acc = 0.f;
    #pragma unroll
    for (int k = 0; k < 2; ++k) {
        const int j = t * 2 + k;
        const float4 w = wrow[j];
        const float4 c = (j < Hdim / 4) ? ev[j] : cv[j - Hdim / 4];
        acc += w.x * c.x + w.y * c.y + w.z * c.z + w.w * c.w;
    }
    acc = blockReduceSum<4>(acc, red);
    if (t == 0) cvec[r] = fmaxf(acc + bc[r], 0.f);
}

// ---------- K5: gi rows j, j+H, j+2H + GRU gate combine → h_new[j] ---------
__global__ __launch_bounds__(256) void k_gru(
    const float* __restrict__ Wih, const float* __restrict__ bih,
    const float* __restrict__ gh, const float* __restrict__ cvec,
    const float* __restrict__ hidden, float* __restrict__ hnew,
    float* __restrict__ out_h)
{
    __shared__ float red[4];
    const int t = threadIdx.x, j = blockIdx.x;              // 1024 blocks
    const float4 c = ((const float4*)cvec)[t];
    const float4 a = ((const float4*)(Wih + (size_t)j * Hdim))[t];
    const float4 b = ((const float4*)(Wih + (size_t)(j + Hdim) * Hdim))[t];
    const float4 d = ((const float4*)(Wih + (size_t)(j + 2 * Hdim) * Hdim))[t];
    float s0 = a.x * c.x + a.y * c.y + a.z * c.z + a.w * c.w;
    float s1 = b.x * c.x + b.y * c.y + b.z * c.z + b.w * c.w;
    float s2 = d.x * c.x + d.y * c.y + d.z * c.z + d.w * c.w;
    s0 = blockReduceSum<4>(s0, red);
    s1 = blockReduceSum<4>(s1, red);
    s2 = blockReduceSum<4>(s2, red);
    if (t == 0) {
        const float gir = s0 + bih[j];
        const float giz = s1 + bih[j + Hdim];
        const float gin = s2 + bih[j + 2 * Hdim];
        const float rr = 1.f / (1.f + __expf(-(gir + gh[j])));
        const float zz = 1.f / (1.f + __expf(-(giz + gh[j + Hdim])));
        const float nn = tanhf(gin + rr * gh[j + 2 * Hdim]);
        const float h = (1.f - zz) * nn + zz * hidden[j];
        hnew[j]  = h;
        out_h[j] = h;                                       // output 2
    }
}

// ---------- K6: logits[r] = Wo[r,:]·h_new + bo[r] (50257 blocks, 206 MB) ---
__global__ __launch_bounds__(256) void k_logits(
    const float* __restrict__ Wo, const float* __restrict__ bo,
    const float* __restrict__ h, float* __restrict__ logits)
{
    __shared__ float red[4];
    const int r = blockIdx.x, t = threadIdx.x;
    const float4 w = ((const float4*)(Wo + (size_t)r * Hdim))[t];
    const float4 hv = ((const float4*)h)[t];
    float acc = w.x * hv.x + w.y * hv.y + w.z * hv.z + w.w * hv.w;
    acc = waveReduceSum(acc);
    if ((t & 63) == 0) red[t >> 6] = acc;
    __syncthreads();
    if (t == 0) logits[r] = red[0] + red[1] + red[2] + red[3] + bo[r];
}

// ---------- K7a: per-block online logsumexp partials over logits ----------
__global__ __launch_bounds__(256) void k_lse_part(
    const float* __restrict__ logits, float* __restrict__ pm, float* __restrict__ ps)
{
    __shared__ float redm[4], reds[4];
    const int gid = blockIdx.x * 256 + threadIdx.x;
    float m = -1e30f, s = 0.f;
    for (int i = gid; i < Vdim; i += 64 * 256) {
        const float v = logits[i];
        const float nm = fmaxf(m, v);
        s = s * __expf(m - nm) + __expf(v - nm);
        m = nm;
    }
    #pragma unroll
    for (int off = 32; off > 0; off >>= 1) {
        const float om = __shfl_down(m, off, 64);
        const float os = __shfl_down(s, off, 64);
        const float nm = fmaxf(m, om);
        s = s * __expf(m - nm) + os * __expf(om - nm);
        m = nm;
    }
    const int lane = threadIdx.x & 63, wid = threadIdx.x >> 6;
    if (lane == 0) { redm[wid] = m; reds[wid] = s; }
    __syncthreads();
    if (threadIdx.x == 0) {
        float M = redm[0], S = reds[0];
        #pragma unroll
        for (int i = 1; i < 4; i++) {
            const float nm = fmaxf(M, redm[i]);
            S = S * __expf(M - nm) + reds[i] * __expf(redm[i] - nm);
            M = nm;
        }
        pm[blockIdx.x] = M; ps[blockIdx.x] = S;
    }
}

// ---------- K7b: combine 64 partials → logZ ----------
__global__ __launch_bounds__(64) void k_lse_final(
    const float* __restrict__ pm, const float* __restrict__ ps,
    float* __restrict__ logZ)
{
    const int t = threadIdx.x;
    float m = pm[t], s = ps[t];
    #pragma unroll
    for (int off = 32; off > 0; off >>= 1) {
        const float om = __shfl_down(m, off, 64);
        const float os = __shfl_down(s, off, 64);
        const float nm = fmaxf(m, om);
        s = s * __expf(m - nm) + os * __expf(om - nm);
        m = nm;
    }
    if (t == 0) logZ[0] = m + logf(s);
}

// ---------- K8: in-place log_softmax: out[i] -= logZ ----------
__global__ __launch_bounds__(256) void k_out(
    float* __restrict__ out, const float* __restrict__ logZ)
{
    const int i = blockIdx.x * 256 + threadIdx.x;
    if (i < Vdim) out[i] = out[i] - logZ[0];
}

extern "C" void kernel_launch(void* const* d_in, const int* in_sizes, int n_in,
                              void* d_out, int out_size, void* d_ws, size_t ws_size,
                              hipStream_t stream)
{
    const int*   x      = (const int*)  d_in[0];
    const float* hidden = (const float*)d_in[1];   // [1,1,H]
    const float* enc    = (const float*)d_in[2];   // [L,H]
    const float* emb    = (const float*)d_in[3];   // [V,H]
    const float* Ww     = (const float*)d_in[4];   // [L,2H]
    const float* bw     = (const float*)d_in[5];   // [L]
    const float* Wc     = (const float*)d_in[6];   // [H,2H]
    const float* bc     = (const float*)d_in[7];   // [H]
    const float* Wih    = (const float*)d_in[8];   // [3H,H]
    const float* Whh    = (const float*)d_in[9];   // [3H,H]
    const float* bih    = (const float*)d_in[10];  // [3H]
    const float* bhh    = (const float*)d_in[11];  // [3H]
    const float* Wo     = (const float*)d_in[12];  // [V,H]
    const float* bo     = (const float*)d_in[13];  // [V]

    float* out      = (float*)d_out;
    float* out_logp = out;                 // [V]  output 1 (logits → in-place log_softmax)
    float* out_h    = out + Vdim;          // [H]  output 2
    float* out_w    = out + Vdim + Hdim;   // [L]  output 3

    float* ws      = (float*)d_ws;
    float* att     = ws;                   // 512
    float* weights = ws + 512;             // 512
    float* wctx    = ws + 1024;            // 1024 (atomic accumulator, zeroed in K2)
    float* cvec    = ws + 2048;            // 1024
    float* gh      = ws + 3072;            // 3072
    float* hnew    = ws + 6144;            // 1024
    float* pm      = ws + 7168;            // 64
    float* psum    = ws + 7232;            // 64
    float* logZ    = ws + 7296;            // 1

    k_att_gh   <<<dim3(Ldim + 3 * Hdim), dim3(256), 0, stream>>>(x, hidden, emb, Ww, bw, Whh, bhh, att, gh);
    k_softmax  <<<dim3(1),               dim3(512), 0, stream>>>(att, weights, out_w, wctx);
    k_wctx     <<<dim3(64),              dim3(256), 0, stream>>>(weights, enc, wctx);
    k_wc       <<<dim3(Hdim),            dim3(256), 0, stream>>>(x, emb, wctx, Wc, bc, cvec);
    k_gru      <<<dim3(Hdim),            dim3(256), 0, stream>>>(Wih, bih, gh, cvec, hidden, hnew, out_h);
    k_logits   <<<dim3(Vdim),            dim3(256), 0, stream>>>(Wo, bo, hnew, out_logp);
    k_lse_part <<<dim3(64),              dim3(256), 0, stream>>>(out_logp, pm, psum);
    k_lse_final<<<dim3(1),               dim3(64),  0, stream>>>(pm, psum, logZ);
    k_out      <<<dim3((Vdim + 255) / 256), dim3(256), 0, stream>>>(out_logp, logZ);
}